// Round 13
// baseline (178.989 us; speedup 1.0000x reference)
//
#include <hip/hip_runtime.h>

namespace {

constexpr int kNXI = 33;                    // x rows tracked: 0..16, 112..127
constexpr int kNMODE = 528;                 // 33*16 slots (497 active)
constexpr int kBiasBlk = 528;               // bias block id
constexpr int kModeBlk = 529;               // 528 mode slots + bias
constexpr int kFwd1Blk = 2048;              // 1 row per 64-thread block

// ws float offsets
constexpr int WS_ALPHA = 0;
constexpr int WS_GAMMA = 1;
constexpr int WS_S = 4;                                 // s[528] complex
constexpr int WS_ZY = WS_S + kNMODE * 2;                // Zy[16][128][16] complex
constexpr int WS_T = WS_ZY;                             // T aliases Zy

constexpr float kTheta = 0.04908738521234052f;          // 2*pi/128

__device__ __forceinline__ float wave_sum(float v) {
  v += __shfl_xor(v, 1);  v += __shfl_xor(v, 2);  v += __shfl_xor(v, 4);
  v += __shfl_xor(v, 8);  v += __shfl_xor(v, 16); v += __shfl_xor(v, 32);
  return v;
}

// ---------------- phase1: 1 wave/mode, W in LDS, barrier-free, readlane-free ----
// Measured primitive costs (R3-R12 tally): s_barrier ~2500cyc at low occupancy,
// v_readlane->VALU ~30cyc/pair. This structure uses NEITHER: lane o's W column
// lives in LDS row o (stride 65 float2 -> 2-way banks = free), state broadcast
// via uniform-address b128 reads, own-lane 8B write; single-wave LDS program
// order replaces all barriers. W never in VGPRs -> no spill (R8's failure).
__global__ __launch_bounds__(64) void fnde_phase1(
    const float* __restrict__ w1, const float* __restrict__ w2,
    const float* __restrict__ flb, const float* __restrict__ lw,
    const float* __restrict__ lb, const float* __restrict__ ts,
    const float* __restrict__ p1w, const float* __restrict__ p1b,
    const float* __restrict__ p2w, const float* __restrict__ p2b,
    const float* __restrict__ z, float* __restrict__ ws) {
  const int b = blockIdx.x;
  const int o = threadIdx.x;                // lane 0..63

  if (b >= kModeBlk) {
    // ---------------- fwd1: forward DFT over ys, one xs-row per wave (R8) ----------
    __shared__ float zrow[128], tcf[128], tsnf[128];
    const int row = b - kModeBlk;           // row = bb*128 + xs
    const int bb = row >> 7, xs = row & 127;
    sincosf((float)o * kTheta, &tsnf[o], &tcf[o]);
    sincosf((float)(o + 64) * kTheta, &tsnf[o + 64], &tcf[o + 64]);
    const float* zp = z + bb * 16384 + xs * 128;
    zrow[o] = zp[o]; zrow[o + 64] = zp[o + 64];
    // single wave: intra-wave LDS program order, no barrier
    const int y = o & 15, part = o >> 4;    // 4 partial groups of 32
    float sre = 0.f, sim = 0.f;
#pragma clang loop unroll(disable)
    for (int j = 0; j < 32; ++j) {
      const int ys = (part << 5) + j;
      const int k = (y * ys) & 127;
      const float zv = zrow[ys];
      sre = fmaf(zv, tcf[k], sre);
      sim = fmaf(-zv, tsnf[k], sim);
    }
    sre += __shfl_xor(sre, 16); sre += __shfl_xor(sre, 32);
    sim += __shfl_xor(sim, 16); sim += __shfl_xor(sim, 32);
    if (o < 16) {
      const int idx = (row * 16 + o) * 2;
      ws[WS_ZY + idx] = sre; ws[WS_ZY + idx + 1] = sim;
    }
    return;
  }

  // ---------------- mode / bias blocks ----------------
  const bool isBias = (b == kBiasBlk);
  int xi = 0, y = 0, m = 0;
  if (!isBias) {
    const int xcd = b & 7, k = b >> 3;      // XCD affinity: 16 y's of one xi share an XCD
    if (k < 64) { xi = xcd * 4 + (k >> 4); y = k & 15; }
    else        { xi = 32;                 y = xcd * 2 + (k - 64); }
    m = y * kNXI + xi;
    const bool inactive = (y == 0) ? (xi > 16) : (xi == 16);
    if (inactive) {
      if (o == 0) { ws[WS_S + 2 * m] = 0.f; ws[WS_S + 2 * m + 1] = 0.f; }
      return;
    }
  }

  __shared__ __align__(16) float2 Wl[64 * 65];   // row o = column o of W, stride 65
  __shared__ __align__(16) float2 xb[64];

  const float t0 = ts[0], t1 = ts[1], t2 = ts[2], t3 = ts[3], t4 = ts[4];
  const float h0 = t1 - t0, h1 = t2 - t1, h2 = t3 - t2, h3 = t4 - t3;

  const float lwc = lw[o];
  float zr = isBias ? lb[o] : lwc, zi = 0.f;
  xb[o] = make_float2(zr, zi);

  // staging source pointers
  const bool herm = isBias || (y == 0);     // bias reuses the (0,0) Hermitian path
  const float* srcA;
  const float* srcB = nullptr;
  bool hasA = true;
  if (!herm) {
    srcA = (xi <= 15) ? (w1 + (xi * 16 + y) * 2)
                      : (w2 + ((xi - 17) * 16 + y) * 2);
  } else {
    hasA = (xi <= 15);
    srcA = w1 + xi * 32;
    srcB = (xi >= 1) ? (w2 + (16 - xi) * 32) : w1;  // (0,0): 0.5*(w1+conj(w1)) = Re(w1)
  }

  float2* const wrow = &Wl[o * 65];

#pragma clang loop unroll(disable)
  for (int l = 0; l < 3; ++l) {
    // ---- stage W[:,o] into LDS row o (64 x 8B gathers; 2-way banks = free) ----
    if (!herm) {
      const float* lp = srcA + o * 512 + (size_t)l * 2097152;
#pragma clang loop unroll_count(8)
      for (int i = 0; i < 64; ++i)
        wrow[i] = *reinterpret_cast<const float2*>(lp + (size_t)i * 32768);
    } else {
      const float* lpA = srcA + o * 512 + (size_t)l * 2097152;
      const float* lpB = srcB + o * 512 + (size_t)l * 2097152;
#pragma clang loop unroll_count(8)
      for (int i = 0; i < 64; ++i) {
        const float2 a = hasA ? *reinterpret_cast<const float2*>(lpA + (size_t)i * 32768)
                              : make_float2(0.f, 0.f);
        const float2 bb2 = *reinterpret_cast<const float2*>(lpB + (size_t)i * 32768);
        wrow[i] = make_float2(0.5f * (a.x + bb2.x), 0.5f * (a.y - bb2.y));
      }
    }
    const float bia = isBias ? flb[l * 64 + o] : 0.f;

#pragma clang loop unroll(disable)
    for (int step = 0; step < 4; ++step) {
      const float h = (step == 0) ? h0 : (step == 1) ? h1 : (step == 2) ? h2 : h3;
      float accr = 0.f, acci = 0.f;
#pragma clang loop unroll(disable)
      for (int st = 0; st < 4; ++st) {
        // ---- matvec: uniform b128 x-broadcast + contiguous own-row W reads ----
        float pr0 = 0.f, pi0 = 0.f, pr1 = 0.f, pi1 = 0.f;
#pragma unroll
        for (int ii = 0; ii < 64; ii += 2) {
          const float4 xx = *reinterpret_cast<const float4*>(&xb[ii]);  // x[ii], x[ii+1]
          const float2 w0 = wrow[ii], w1v = wrow[ii + 1];
          pr0 = fmaf(w0.x,  xx.x, pr0);  pr0 = fmaf(-w0.y,  xx.y, pr0);
          pi0 = fmaf(w0.x,  xx.y, pi0);  pi0 = fmaf(w0.y,   xx.x, pi0);
          pr1 = fmaf(w1v.x, xx.z, pr1);  pr1 = fmaf(-w1v.y, xx.w, pr1);
          pi1 = fmaf(w1v.x, xx.w, pi1);  pi1 = fmaf(w1v.y,  xx.z, pi1);
        }
        const float kr = pr0 + pr1 + bia, ki = pi0 + pi1;
        const float wsm = (st == 1 || st == 2) ? 2.f : 1.f;
        accr = fmaf(wsm, kr, accr); acci = fmaf(wsm, ki, acci);
        float ur, ui;
        if (st < 3) {
          const float cm = (st < 2) ? 0.5f * h : h;
          ur = fmaf(cm, kr, zr); ui = fmaf(cm, ki, zi);
        } else {
          zr = fmaf(h * (1.f / 6.f), accr, zr);
          zi = fmaf(h * (1.f / 6.f), acci, zi);
          ur = zr; ui = zi;
        }
        xb[o] = make_float2(ur, ui);    // own-lane 8B write; program-order for next stage
      }
    }
  }

  // ---- epilogue: q = p2*p1 (after the chain so it can't delay stage 0) ----
  float q = 0.f;
#pragma clang loop unroll(disable)
  for (int p = 0; p < 64; ++p) q = fmaf(p2w[p], p1w[p * 64 + o], q);

  if (isBias) {
    const float g = wave_sum(fmaf(p2w[o], p1b[o], q * zr));
    if (o == 0) ws[WS_GAMMA] = g + p2b[0];
  } else {
    const float sr = wave_sum(q * (zr - lwc));
    const float si = wave_sum(q * zi);
    if (o == 0) { ws[WS_S + 2 * m] = sr; ws[WS_S + 2 * m + 1] = si; }
    if (m == 0) {
      const float a = wave_sum(q * lwc);
      if (o == 0) ws[WS_ALPHA] = a;
    }
  }
}

// ---------------- fused: x-DFT at tracked rows, *S, inverse over xs ----------------
__global__ void fnde_mid(float* __restrict__ ws) {
  const int b = blockIdx.x >> 4, y = blockIdx.x & 15;
  const int t = threadIdx.x;              // 128
  __shared__ float cr[128], ci[128], tc[128], tsn[128], Sre[kNXI], Sim[kNXI];
  sincosf((float)t * kTheta, &tsn[t], &tc[t]);
  int idx = ((b * 128 + t) * 16 + y) * 2;
  cr[t] = ws[WS_ZY + idx]; ci[t] = ws[WS_ZY + idx + 1];
  __syncthreads();
  if (t < kNXI) {
    int x = (t <= 16) ? t : t + 95;
    float ar = 0.f, ai = 0.f;
    for (int xs = 0; xs < 128; ++xs) {
      int k = (x * xs) & 127;
      float c = tc[k], s = tsn[k];
      ar += cr[xs] * c + ci[xs] * s;
      ai += ci[xs] * c - cr[xs] * s;
    }
    int mm = y * kNXI + t;
    float sr = ws[WS_S + 2 * mm], si = ws[WS_S + 2 * mm + 1];
    Sre[t] = sr * ar - si * ai;
    Sim[t] = sr * ai + si * ar;
  }
  __syncthreads();
  const int xs = t;
  float ar, ai;
  if (y > 0) {
    ar = 0.f; ai = 0.f;
    for (int xj = 0; xj < kNXI; ++xj) {
      int x = (xj <= 16) ? xj : xj + 95;
      int k = (x * xs) & 127;
      float c = tc[k], s = tsn[k];
      ar += Sre[xj] * c - Sim[xj] * s;   // e^{+i}
      ai += Sre[xj] * s + Sim[xj] * c;
    }
  } else {
    ar = Sre[0]; ai = 0.f;               // x-col 0: Hermitian pairs -> real
    for (int xj = 1; xj <= 16; ++xj) {
      int k = (xj * xs) & 127;
      ar += 2.f * (Sre[xj] * tc[k] - Sim[xj] * tsn[k]);
    }
  }
  ws[WS_T + idx] = ar; ws[WS_T + idx + 1] = ai;   // in-place per (b,y) slice
}

// ---------------- inverse stage 2 + epilogue ----------------
__global__ void fnde_final(const float* __restrict__ z, const float* __restrict__ ws,
                           float* __restrict__ out) {
  const int bid = blockIdx.x;             // b*128 + xs
  const int b = bid >> 7, xs = bid & 127;
  const int t = threadIdx.x;              // 128 (ys)
  __shared__ float Tre[16], Tim[16], tc[128], tsn[128];
  sincosf((float)t * kTheta, &tsn[t], &tc[t]);
  if (t < 16) {
    int idx = ((b * 128 + xs) * 16 + t) * 2;
    Tre[t] = ws[WS_T + idx]; Tim[t] = ws[WS_T + idx + 1];
  }
  __syncthreads();
  float acc = Tre[0];
  for (int y = 1; y < 16; ++y) {
    int k = (y * t) & 127;
    acc += 2.f * (Tre[y] * tc[k] - Tim[y] * tsn[k]);   // 2*Re(T * e^{+i})
  }
  float val = ws[WS_ALPHA] * z[b * 16384 + xs * 128 + t] + ws[WS_GAMMA]
            + acc * (1.f / 16384.f);
  out[b * 16384 + xs * 128 + t] = val;
}

}  // namespace

extern "C" void kernel_launch(void* const* d_in, const int* in_sizes, int n_in,
                              void* d_out, int out_size, void* d_ws, size_t ws_size,
                              hipStream_t stream) {
  (void)in_sizes; (void)n_in; (void)out_size; (void)ws_size;
  const float* z   = (const float*)d_in[0];
  const float* lw  = (const float*)d_in[1];
  const float* lb  = (const float*)d_in[2];
  const float* w1  = (const float*)d_in[3];
  const float* w2  = (const float*)d_in[4];
  const float* flb = (const float*)d_in[5];
  const float* p1w = (const float*)d_in[6];
  const float* p1b = (const float*)d_in[7];
  const float* p2w = (const float*)d_in[8];
  const float* p2b = (const float*)d_in[9];
  const float* ts  = (const float*)d_in[10];
  float* ws = (float*)d_ws;
  float* out = (float*)d_out;

  fnde_phase1<<<dim3(kModeBlk + kFwd1Blk), dim3(64), 0, stream>>>(
      w1, w2, flb, lw, lb, ts, p1w, p1b, p2w, p2b, z, ws);
  fnde_mid<<<dim3(256), dim3(128), 0, stream>>>(ws);
  fnde_final<<<dim3(2048), dim3(128), 0, stream>>>(z, ws, out);
}

// Round 14
// 121.577 us; speedup vs baseline: 1.4722x; 1.4722x over previous
//
#include <hip/hip_runtime.h>

namespace {

constexpr int kNXI = 33;                    // x rows tracked: 0..16, 112..127
constexpr int kNMODE = 528;                 // 33*16 slots (497 active)
constexpr int kBiasBlk = 528;               // bias block id
constexpr int kModeBlk = 529;               // 528 mode slots + bias
constexpr int kFwd1Blk = 2048;              // 1 row per 64-thread block

// ws float offsets
constexpr int WS_ALPHA = 0;
constexpr int WS_GAMMA = 1;
constexpr int WS_S = 4;                                 // s[528] complex
constexpr int WS_ZY = WS_S + kNMODE * 2;                // Zy[16][128][16] complex
constexpr int WS_T = WS_ZY;                             // T aliases Zy

constexpr float kTheta = 0.04908738521234052f;          // 2*pi/128

__device__ __forceinline__ float wave_sum(float v) {
  v += __shfl_xor(v, 1);  v += __shfl_xor(v, 2);  v += __shfl_xor(v, 4);
  v += __shfl_xor(v, 8);  v += __shfl_xor(v, 16); v += __shfl_xor(v, 32);
  return v;
}

// wave_ror:1 (DPP 0x13C): dst[i] = src[(i-1)&63]  (scan convention: row_shr/ror
// move data toward higher lanes). After s applications lane L holds x[(L-s)&63].
__device__ __forceinline__ float ror1(float v) {
  return __uint_as_float(__builtin_amdgcn_mov_dpp(
      (int)__float_as_uint(v), 0x13C, 0xF, 0xF, true));
}

// ---------------- phase1: 1 wave/mode, W in VGPR, systolic DPP-rotation matvec ----
// Chain primitives tally (R3-R13): readlane ~30cyc/pair, barrier ~2.5kcyc,
// per-lane ds_read latency unbatchable. This structure uses NONE of them:
// x broadcast by rotating x through the lanes with v_mov_dpp wave_ror:1 (pure
// VALU), W column pre-gathered in rotation order. Zero LDS/barrier/SALU in
// the 48-stage serial chain.
__global__ __launch_bounds__(64) void fnde_phase1(
    const float* __restrict__ w1, const float* __restrict__ w2,
    const float* __restrict__ flb, const float* __restrict__ lw,
    const float* __restrict__ lb, const float* __restrict__ ts,
    const float* __restrict__ p1w, const float* __restrict__ p1b,
    const float* __restrict__ p2w, const float* __restrict__ p2b,
    const float* __restrict__ z, float* __restrict__ ws) {
  const int b = blockIdx.x;
  const int o = threadIdx.x;                // lane 0..63 (output channel)

  if (b >= kModeBlk) {
    // ---------------- fwd1: forward DFT over ys, one xs-row per wave ----------------
    __shared__ float zrow[128], tcf[128], tsnf[128];
    const int row = b - kModeBlk;           // row = bb*128 + xs
    const int bb = row >> 7, xs = row & 127;
    sincosf((float)o * kTheta, &tsnf[o], &tcf[o]);
    sincosf((float)(o + 64) * kTheta, &tsnf[o + 64], &tcf[o + 64]);
    const float* zp = z + bb * 16384 + xs * 128;
    zrow[o] = zp[o]; zrow[o + 64] = zp[o + 64];
    const int y = o & 15, part = o >> 4;    // 4 partial groups of 32
    float sre = 0.f, sim = 0.f;
#pragma clang loop unroll(disable)
    for (int j = 0; j < 32; ++j) {
      const int ys = (part << 5) + j;
      const int k = (y * ys) & 127;
      const float zv = zrow[ys];
      sre = fmaf(zv, tcf[k], sre);
      sim = fmaf(-zv, tsnf[k], sim);
    }
    sre += __shfl_xor(sre, 16); sre += __shfl_xor(sre, 32);
    sim += __shfl_xor(sim, 16); sim += __shfl_xor(sim, 32);
    if (o < 16) {
      const int idx = (row * 16 + o) * 2;
      ws[WS_ZY + idx] = sre; ws[WS_ZY + idx + 1] = sim;
    }
    return;
  }

  // ---------------- mode / bias blocks ----------------
  const bool isBias = (b == kBiasBlk);
  int xi = 0, y = 0, m = 0;
  if (!isBias) {
    const int xcd = b & 7, k = b >> 3;      // XCD affinity: 16 y's of one xi share an XCD
    if (k < 64) { xi = xcd * 4 + (k >> 4); y = k & 15; }
    else        { xi = 32;                 y = xcd * 2 + (k - 64); }
    m = y * kNXI + xi;
    const bool inactive = (y == 0) ? (xi > 16) : (xi == 16);
    if (inactive) {
      if (o == 0) { ws[WS_S + 2 * m] = 0.f; ws[WS_S + 2 * m + 1] = 0.f; }
      return;
    }
  }

  const float t0 = ts[0], t1 = ts[1], t2 = ts[2], t3 = ts[3], t4 = ts[4];
  const float h0 = t1 - t0, h1 = t2 - t1, h2 = t3 - t2, h3 = t4 - t3;

  const float lwc = lw[o];
  float zr = isBias ? lb[o] : lwc, zi = 0.f;

  // staging pointers: element (l, i, o) at float offset l*2097152 + i*32768 + o*512 (+moff)
  const bool herm = isBias || (y == 0);
  const float* srcA;
  const float* srcB = nullptr;
  bool hasA = true;
  if (!herm) {
    srcA = (xi <= 15) ? (w1 + (xi * 16 + y) * 2)
                      : (w2 + ((xi - 17) * 16 + y) * 2);
  } else {
    hasA = (xi <= 15);
    srcA = w1 + xi * 32;
    srcB = (xi >= 1) ? (w2 + (16 - xi) * 32) : w1;  // (0,0): Re(w1) — bias uses this too
  }

  float2 Wc[64];                            // Wc[s] = W[(o-s)&63][o], rotation order

#pragma clang loop unroll(disable)
  for (int l = 0; l < 3; ++l) {
    // ---- gather W column o in rotation order ----
    if (!herm) {
      const float* lp = srcA + o * 512 + (size_t)l * 2097152;
#pragma unroll
      for (int s = 0; s < 64; ++s) {
        const int i_s = (o + 64 - s) & 63;
        Wc[s] = *reinterpret_cast<const float2*>(lp + (size_t)i_s * 32768);
      }
    } else {
      const float* lpA = srcA + o * 512 + (size_t)l * 2097152;
      const float* lpB = srcB + o * 512 + (size_t)l * 2097152;
#pragma unroll
      for (int s = 0; s < 64; ++s) {
        const int i_s = (o + 64 - s) & 63;
        const float2 a = hasA ? *reinterpret_cast<const float2*>(lpA + (size_t)i_s * 32768)
                              : make_float2(0.f, 0.f);
        const float2 bb2 = *reinterpret_cast<const float2*>(lpB + (size_t)i_s * 32768);
        Wc[s] = make_float2(0.5f * (a.x + bb2.x), 0.5f * (a.y - bb2.y));
      }
    }
    const float bia = isBias ? flb[l * 64 + o] : 0.f;

#pragma clang loop unroll(disable)
    for (int step = 0; step < 4; ++step) {
      const float h = (step == 0) ? h0 : (step == 1) ? h1 : (step == 2) ? h2 : h3;
      float accr = 0.f, acci = 0.f;
      float ur = zr, ui = zi;
#pragma clang loop unroll(disable)
      for (int st = 0; st < 4; ++st) {
        // ---- systolic matvec: rotate x through lanes, 4 accumulator pairs ----
        float y0r = 0.f, y0i = 0.f, y1r = 0.f, y1i = 0.f;
        float y2r = 0.f, y2i = 0.f, y3r = 0.f, y3i = 0.f;
        float xr_c = ur, xi_c = ui;
#pragma unroll
        for (int s = 0; s < 64; s += 4) {
          y0r = fmaf(Wc[s].x, xr_c, y0r);      y0r = fmaf(-Wc[s].y, xi_c, y0r);
          y0i = fmaf(Wc[s].x, xi_c, y0i);      y0i = fmaf(Wc[s].y,  xr_c, y0i);
          xr_c = ror1(xr_c); xi_c = ror1(xi_c);
          y1r = fmaf(Wc[s + 1].x, xr_c, y1r);  y1r = fmaf(-Wc[s + 1].y, xi_c, y1r);
          y1i = fmaf(Wc[s + 1].x, xi_c, y1i);  y1i = fmaf(Wc[s + 1].y,  xr_c, y1i);
          xr_c = ror1(xr_c); xi_c = ror1(xi_c);
          y2r = fmaf(Wc[s + 2].x, xr_c, y2r);  y2r = fmaf(-Wc[s + 2].y, xi_c, y2r);
          y2i = fmaf(Wc[s + 2].x, xi_c, y2i);  y2i = fmaf(Wc[s + 2].y,  xr_c, y2i);
          xr_c = ror1(xr_c); xi_c = ror1(xi_c);
          y3r = fmaf(Wc[s + 3].x, xr_c, y3r);  y3r = fmaf(-Wc[s + 3].y, xi_c, y3r);
          y3i = fmaf(Wc[s + 3].x, xi_c, y3i);  y3i = fmaf(Wc[s + 3].y,  xr_c, y3i);
          xr_c = ror1(xr_c); xi_c = ror1(xi_c);
        }
        const float kr = (y0r + y1r) + (y2r + y3r) + bia;
        const float ki = (y0i + y1i) + (y2i + y3i);
        const float wsm = (st == 1 || st == 2) ? 2.f : 1.f;
        accr = fmaf(wsm, kr, accr); acci = fmaf(wsm, ki, acci);
        if (st < 3) {
          const float cm = (st < 2) ? 0.5f * h : h;
          ur = fmaf(cm, kr, zr); ui = fmaf(cm, ki, zi);
        } else {
          zr = fmaf(h * (1.f / 6.f), accr, zr);
          zi = fmaf(h * (1.f / 6.f), acci, zi);
        }
      }
    }
  }

  // ---- epilogue: q = p2*p1 (once, after the chain) ----
  float q = 0.f;
#pragma clang loop unroll(disable)
  for (int p = 0; p < 64; ++p) q = fmaf(p2w[p], p1w[p * 64 + o], q);

  if (isBias) {
    const float g = wave_sum(fmaf(p2w[o], p1b[o], q * zr));
    if (o == 0) ws[WS_GAMMA] = g + p2b[0];
  } else {
    const float sr = wave_sum(q * (zr - lwc));
    const float si = wave_sum(q * zi);
    if (o == 0) { ws[WS_S + 2 * m] = sr; ws[WS_S + 2 * m + 1] = si; }
    if (m == 0) {
      const float a = wave_sum(q * lwc);
      if (o == 0) ws[WS_ALPHA] = a;
    }
  }
}

// ---------------- fused: x-DFT at tracked rows, *S, inverse over xs ----------------
__global__ void fnde_mid(float* __restrict__ ws) {
  const int b = blockIdx.x >> 4, y = blockIdx.x & 15;
  const int t = threadIdx.x;              // 128
  __shared__ float cr[128], ci[128], tc[128], tsn[128], Sre[kNXI], Sim[kNXI];
  sincosf((float)t * kTheta, &tsn[t], &tc[t]);
  int idx = ((b * 128 + t) * 16 + y) * 2;
  cr[t] = ws[WS_ZY + idx]; ci[t] = ws[WS_ZY + idx + 1];
  __syncthreads();
  if (t < kNXI) {
    int x = (t <= 16) ? t : t + 95;
    float ar = 0.f, ai = 0.f;
    for (int xs = 0; xs < 128; ++xs) {
      int k = (x * xs) & 127;
      float c = tc[k], s = tsn[k];
      ar += cr[xs] * c + ci[xs] * s;
      ai += ci[xs] * c - cr[xs] * s;
    }
    int mm = y * kNXI + t;
    float sr = ws[WS_S + 2 * mm], si = ws[WS_S + 2 * mm + 1];
    Sre[t] = sr * ar - si * ai;
    Sim[t] = sr * ai + si * ar;
  }
  __syncthreads();
  const int xs = t;
  float ar, ai;
  if (y > 0) {
    ar = 0.f; ai = 0.f;
    for (int xj = 0; xj < kNXI; ++xj) {
      int x = (xj <= 16) ? xj : xj + 95;
      int k = (x * xs) & 127;
      float c = tc[k], s = tsn[k];
      ar += Sre[xj] * c - Sim[xj] * s;   // e^{+i}
      ai += Sre[xj] * s + Sim[xj] * c;
    }
  } else {
    ar = Sre[0]; ai = 0.f;               // x-col 0: Hermitian pairs -> real
    for (int xj = 1; xj <= 16; ++xj) {
      int k = (xj * xs) & 127;
      ar += 2.f * (Sre[xj] * tc[k] - Sim[xj] * tsn[k]);
    }
  }
  ws[WS_T + idx] = ar; ws[WS_T + idx + 1] = ai;   // in-place per (b,y) slice
}

// ---------------- inverse stage 2 + epilogue ----------------
__global__ void fnde_final(const float* __restrict__ z, const float* __restrict__ ws,
                           float* __restrict__ out) {
  const int bid = blockIdx.x;             // b*128 + xs
  const int b = bid >> 7, xs = bid & 127;
  const int t = threadIdx.x;              // 128 (ys)
  __shared__ float Tre[16], Tim[16], tc[128], tsn[128];
  sincosf((float)t * kTheta, &tsn[t], &tc[t]);
  if (t < 16) {
    int idx = ((b * 128 + xs) * 16 + t) * 2;
    Tre[t] = ws[WS_T + idx]; Tim[t] = ws[WS_T + idx + 1];
  }
  __syncthreads();
  float acc = Tre[0];
  for (int y = 1; y < 16; ++y) {
    int k = (y * t) & 127;
    acc += 2.f * (Tre[y] * tc[k] - Tim[y] * tsn[k]);   // 2*Re(T * e^{+i})
  }
  float val = ws[WS_ALPHA] * z[b * 16384 + xs * 128 + t] + ws[WS_GAMMA]
            + acc * (1.f / 16384.f);
  out[b * 16384 + xs * 128 + t] = val;
}

}  // namespace

extern "C" void kernel_launch(void* const* d_in, const int* in_sizes, int n_in,
                              void* d_out, int out_size, void* d_ws, size_t ws_size,
                              hipStream_t stream) {
  (void)in_sizes; (void)n_in; (void)out_size; (void)ws_size;
  const float* z   = (const float*)d_in[0];
  const float* lw  = (const float*)d_in[1];
  const float* lb  = (const float*)d_in[2];
  const float* w1  = (const float*)d_in[3];
  const float* w2  = (const float*)d_in[4];
  const float* flb = (const float*)d_in[5];
  const float* p1w = (const float*)d_in[6];
  const float* p1b = (const float*)d_in[7];
  const float* p2w = (const float*)d_in[8];
  const float* p2b = (const float*)d_in[9];
  const float* ts  = (const float*)d_in[10];
  float* ws = (float*)d_ws;
  float* out = (float*)d_out;

  fnde_phase1<<<dim3(kModeBlk + kFwd1Blk), dim3(64), 0, stream>>>(
      w1, w2, flb, lw, lb, ts, p1w, p1b, p2w, p2b, z, ws);
  fnde_mid<<<dim3(256), dim3(128), 0, stream>>>(ws);
  fnde_final<<<dim3(2048), dim3(128), 0, stream>>>(z, ws, out);
}

// Round 15
// 106.934 us; speedup vs baseline: 1.6738x; 1.1369x over previous
//
#include <hip/hip_runtime.h>

namespace {

constexpr int kNXI = 33;                    // x rows tracked: 0..16, 112..127
constexpr int kNMODE = 528;                 // 33*16 slots (497 active)
constexpr int kChainBlk = 1061;             // 1056 mode chain blocks (R/L) + 5 gamma
constexpr int kFwd1Blk = 1024;              // 2 rows per 256-thread block

// ws float offsets
constexpr int WS_Q = 0;                     // q[64] (written by G5 block)
constexpr int WS_GAMMA = 64;                // written by mid
constexpr int WS_ALPHA = 65;                // written by mid
constexpr int WS_G1 = 68;                   // u_lb[64]   = Phi1^2 A0 lb      (real)
constexpr int WS_G2 = 132;                  // c0x[64]    = Phi1^2 c0         (real)
constexpr int WS_G3 = 196;                  // c1[64]                         (real)
constexpr int WS_G4 = 260;                  // c2[64]                         (real)
constexpr int WS_G5 = 324;                  // w2v[64]    = A2^T q            (real)
constexpr int WS_U = 392;                   // u[528][64] complex (right chains)
constexpr int WS_V = WS_U + kNMODE * 128;   // v[528][64] complex (left chains)
constexpr int WS_ZY = WS_V + kNMODE * 128;  // Zy[16][128][16] complex
constexpr int WS_T = WS_ZY;                 // T aliases Zy

constexpr float kTheta = 0.04908738521234052f;          // 2*pi/128

// ---------------- phase1: depth-24 bilinear chains (R6 4-wave mechanics) + fwd1 ----
// s[m] = q^T G lw - q.lw with G = A2 A1 A0, A_l = Phi_l^4 (RK4). Bilinear split:
// right u = Phi1^2 A0 lw (24 stages), left v = (Phi1^2)^T A2^T q (24 stages,
// transposed gathers), s = v.u - q.lw (algebra proven correct in R11). The
// depth-48 bias chain decomposes into 5 independent depth<=24 real chains via
// e3 = A2A1A0 lb + A2A1 c0 + A2 c1 + c2 (c_l = 4 biased RK4 steps from 0).
// Each chain = one 256-thread block with R6's measured-best stage mechanics
// (4-wave i-split, 1 barrier/stage, ~1.73us/stage). R/L of one mode share an
// XCD (same weight lines in that L2).
__global__ __launch_bounds__(256) void fnde_phase1(
    const float* __restrict__ w1, const float* __restrict__ w2,
    const float* __restrict__ flb, const float* __restrict__ lw,
    const float* __restrict__ lb, const float* __restrict__ ts,
    const float* __restrict__ p1w, const float* __restrict__ p2w,
    const float* __restrict__ z, float* __restrict__ ws) {
  const int b = blockIdx.x;
  const int t = threadIdx.x;

  if (b >= kChainBlk) {
    // ---------------- fwd1: forward DFT over ys (2 rows per block) ----------------
    __shared__ float zrow2[2][128], tcf[128], tsnf[128], rre2[2][128], rim2[2][128];
    const int bid = b - kChainBlk;
    const int r = t >> 7, tt = t & 127;
    const int row = bid * 2 + r;          // row = bb*128 + xs
    const int bb = row >> 7, xs = row & 127;
    if (r == 0) sincosf((float)tt * kTheta, &tsnf[tt], &tcf[tt]);
    zrow2[r][tt] = z[bb * 16384 + xs * 128 + tt];
    __syncthreads();
    int y = tt & 15, part = tt >> 4;      // 8 partial groups
    float sre = 0.f, sim = 0.f;
#pragma clang loop unroll(disable)
    for (int j = 0; j < 16; ++j) {
      int ys = (part << 4) + j;
      int k = (y * ys) & 127;
      float zv = zrow2[r][ys];
      sre += zv * tcf[k];
      sim -= zv * tsnf[k];
    }
    rre2[r][tt] = sre; rim2[r][tt] = sim;
    __syncthreads();
    if (tt < 16) {
      float ar = 0.f, ai = 0.f;
#pragma clang loop unroll(disable)
      for (int pp = 0; pp < 8; ++pp) { ar += rre2[r][(pp << 4) + tt]; ai += rim2[r][(pp << 4) + tt]; }
      int idx = (row * 16 + tt) * 2;
      ws[WS_ZY + idx] = ar; ws[WS_ZY + idx + 1] = ai;
    }
    return;
  }

  const int w = t >> 6, o = t & 63;       // wave 0..3, channel lane

  // ---------------- decode block -> chain parameters ----------------
  int seg0L = 0, seg0N = 4, seg1L = 1, seg1N = 2;
  int biasSeg = -1;
  bool trans = false, herm = false, hasA = true, cplx = true;
  bool needQ = false, writeQ = false, startLw = false, startLb = false;
  const float* sA = w1;
  const float* sB = w1;
  int outOff = -1;

  if (b < 1056) {
    const int xcd = b & 7, kk = b >> 3;
    const int k = kk >> 1, side = kk & 1;  // R/L of one slot share an XCD
    int xi, y;
    if (k < 64) { xi = xcd * 4 + (k >> 4); y = k & 15; }
    else        { xi = 32;                 y = xcd * 2 + (k - 64); }
    const int m = y * kNXI + xi;
    const bool inactive = (y == 0) ? (xi > 16) : (xi == 16);
    if (inactive) return;
    herm = (y == 0);
    if (!herm) {
      sA = (xi <= 15) ? (w1 + (xi * 16 + y) * 2) : (w2 + ((xi - 17) * 16 + y) * 2);
    } else {
      hasA = (xi <= 15);
      sA = w1 + xi * 32;
      sB = (xi >= 1) ? (w2 + (16 - xi) * 32) : w1;
    }
    if (side == 0) { startLw = true;             outOff = WS_U + m * 128; }
    else           { seg0L = 2; trans = true; needQ = true; outOff = WS_V + m * 128; }
  } else {
    const int g = b - 1056;
    herm = true; hasA = true; sA = w1; sB = w1; cplx = false;
    if      (g == 0) { startLb = true;                         outOff = WS_G1; }
    else if (g == 1) { biasSeg = 0;                            outOff = WS_G2; }
    else if (g == 2) { seg0L = 1; seg1N = 0; biasSeg = 0;      outOff = WS_G3; }
    else if (g == 3) { seg0L = 2; seg1N = 0; biasSeg = 0;      outOff = WS_G4; }
    else             { seg0L = 2; seg1N = 0; trans = true; needQ = true; writeQ = true;
                       outOff = WS_G5; }
  }

  float qv = 0.f;
  if (needQ) {
#pragma clang loop unroll(disable)
    for (int p = 0; p < 64; ++p) qv = fmaf(p2w[p], p1w[p * 64 + o], qv);
  }
  if (writeQ && w == 0) ws[WS_Q + o] = qv;

  float zr = startLw ? lw[o] : startLb ? lb[o] : needQ ? qv : 0.f;
  float zi = 0.f;

  __shared__ float2 ubuf[4][64];          // per-wave full-state copies
  __shared__ float2 pbuf[2][4][64];       // double-buffered partials
  ubuf[w][o] = make_float2(zr, zi);
  int pb = 0;

  const int segL[2] = {seg0L, seg1L};
  const int segN[2] = {seg0N, seg1N};

#pragma clang loop unroll(disable)
  for (int sg = 0; sg < 2; ++sg) {
    const int l = segL[sg], n = segN[sg];
    if (n == 0) break;                    // uniform per block
    // ---- load Wc[16]: term j -> summation index v = 16w+j ----
    float2 Wc[16];
#pragma unroll
    for (int j = 0; j < 16; ++j) {
      const int v = 16 * w + j;
      const size_t off = (size_t)l * 2097152 +
          (trans ? ((size_t)o * 32768 + (size_t)v * 512)
                 : ((size_t)v * 32768 + (size_t)o * 512));
      if (!herm) {
        Wc[j] = *reinterpret_cast<const float2*>(sA + off);
      } else {
        const float2 a = hasA ? *reinterpret_cast<const float2*>(sA + off)
                              : make_float2(0.f, 0.f);
        const float2 bb2 = *reinterpret_cast<const float2*>(sB + off);
        Wc[j] = make_float2(0.5f * (a.x + bb2.x), 0.5f * (a.y - bb2.y));
      }
    }
    const float bia = (biasSeg == sg) ? flb[l * 64 + o] : 0.f;

#pragma clang loop unroll(disable)
    for (int step = 0; step < n; ++step) {
      const int si_ = trans ? (3 - step) : step;   // transpose reverses step order
      const float h = ts[si_ + 1] - ts[si_];
      float accr = 0.f, acci = 0.f;
#pragma clang loop unroll(disable)
      for (int st = 0; st < 4; ++st) {
        float2 x[16];
#pragma unroll
        for (int jj = 0; jj < 8; ++jj)
          *reinterpret_cast<float4*>(&x[2 * jj]) =
              *reinterpret_cast<const float4*>(&ubuf[w][16 * w + 2 * jj]);
        float pr0 = 0.f, pi0 = 0.f, pr1 = 0.f, pi1 = 0.f;
#pragma unroll
        for (int j = 0; j < 16; j += 2) {
          pr0 = fmaf(Wc[j].x,     x[j].x,     pr0);  pr0 = fmaf(-Wc[j].y,     x[j].y,     pr0);
          pi0 = fmaf(Wc[j].x,     x[j].y,     pi0);  pi0 = fmaf(Wc[j].y,      x[j].x,     pi0);
          pr1 = fmaf(Wc[j + 1].x, x[j + 1].x, pr1);  pr1 = fmaf(-Wc[j + 1].y, x[j + 1].y, pr1);
          pi1 = fmaf(Wc[j + 1].x, x[j + 1].y, pi1);  pi1 = fmaf(Wc[j + 1].y,  x[j + 1].x, pi1);
        }
        pbuf[pb][w][o] = make_float2(pr0 + pr1, pi0 + pi1);
        __syncthreads();
        const float2 q0 = pbuf[pb][0][o], q1 = pbuf[pb][1][o];
        const float2 q2 = pbuf[pb][2][o], q3 = pbuf[pb][3][o];
        const float kr = q0.x + q1.x + q2.x + q3.x + bia;
        const float ki = q0.y + q1.y + q2.y + q3.y;
        const float wsm = (st == 1 || st == 2) ? 2.f : 1.f;
        accr = fmaf(wsm, kr, accr); acci = fmaf(wsm, ki, acci);
        float ur, ui;
        if (st < 3) {
          const float cm = (st < 2) ? 0.5f * h : h;
          ur = fmaf(cm, kr, zr); ui = fmaf(cm, ki, zi);
        } else {
          zr = fmaf(h * (1.f / 6.f), accr, zr);
          zi = fmaf(h * (1.f / 6.f), acci, zi);
          ur = zr; ui = zi;
        }
        ubuf[w][o] = make_float2(ur, ui);
        pb ^= 1;
      }
    }
  }

  if (w == 0) {
    if (cplx) { ws[outOff + 2 * o] = zr; ws[outOff + 2 * o + 1] = zi; }
    else      { ws[outOff + o] = zr; }
  }
}

// ---------------- fused: combine (s,alpha,gamma) + x-DFT + *S + inverse over xs ----
__global__ void fnde_mid(const float* __restrict__ lw, const float* __restrict__ p1b,
                         const float* __restrict__ p2w, const float* __restrict__ p2b,
                         float* __restrict__ ws) {
  const int b = blockIdx.x >> 4, y = blockIdx.x & 15;
  const int t = threadIdx.x;              // 128
  __shared__ float cr[128], ci[128], tc[128], tsn[128], Sre[kNXI], Sim[kNXI];
  sincosf((float)t * kTheta, &tsn[t], &tc[t]);
  int idx = ((b * 128 + t) * 16 + y) * 2;
  cr[t] = ws[WS_ZY + idx]; ci[t] = ws[WS_ZY + idx + 1];

  // gamma / alpha (block 0 only; parallel to the DFT work below)
  if (blockIdx.x == 0 && t == 40) {
    float g = p2b[0];
    for (int p = 0; p < 64; ++p) g += p2w[p] * p1b[p];
    for (int o = 0; o < 64; ++o) g += ws[WS_V + 2 * o] * ws[WS_G1 + o];  // Re(v00).u_lb
    for (int o = 0; o < 64; ++o) g += ws[WS_V + 2 * o] * ws[WS_G2 + o];  // Re(v00).c0x
    for (int o = 0; o < 64; ++o) g += ws[WS_G5 + o] * ws[WS_G3 + o];     // w2v.c1
    for (int o = 0; o < 64; ++o) g += ws[WS_Q + o] * ws[WS_G4 + o];      // q.c2
    ws[WS_GAMMA] = g;
  }
  if (blockIdx.x == 0 && t == 41) {
    float a = 0.f;
    for (int p = 0; p < 64; ++p) a += ws[WS_Q + p] * lw[p];
    ws[WS_ALPHA] = a;
  }
  __syncthreads();
  if (t < kNXI) {
    int x = (t <= 16) ? t : t + 95;
    float ar = 0.f, ai = 0.f;
    for (int xs = 0; xs < 128; ++xs) {
      int k = (x * xs) & 127;
      float c = tc[k], s = tsn[k];
      ar += cr[xs] * c + ci[xs] * s;
      ai += ci[xs] * c - cr[xs] * s;
    }
    // s[m] = v.u - q.lw  (bilinear combine, computed here)
    const int mm = y * kNXI + t;
    const bool act = (y == 0) ? (t <= 16) : (t != 16);
    float sr = 0.f, si = 0.f;
    if (act) {
      const float* up = ws + WS_U + mm * 128;
      const float* vp = ws + WS_V + mm * 128;
      float alpha = 0.f;
      for (int p = 0; p < 64; ++p) alpha += ws[WS_Q + p] * lw[p];
      for (int o = 0; o < 64; ++o) {
        const float ur2 = up[2 * o], ui2 = up[2 * o + 1];
        const float vr2 = vp[2 * o], vi2 = vp[2 * o + 1];
        sr += vr2 * ur2 - vi2 * ui2;
        si += vr2 * ui2 + vi2 * ur2;
      }
      sr -= alpha;
    }
    Sre[t] = sr * ar - si * ai;
    Sim[t] = sr * ai + si * ar;
  }
  __syncthreads();
  const int xs = t;
  float ar, ai;
  if (y > 0) {
    ar = 0.f; ai = 0.f;
    for (int xj = 0; xj < kNXI; ++xj) {
      int x = (xj <= 16) ? xj : xj + 95;
      int k = (x * xs) & 127;
      float c = tc[k], s = tsn[k];
      ar += Sre[xj] * c - Sim[xj] * s;   // e^{+i}
      ai += Sre[xj] * s + Sim[xj] * c;
    }
  } else {
    ar = Sre[0]; ai = 0.f;               // x-col 0: Hermitian pairs -> real
    for (int xj = 1; xj <= 16; ++xj) {
      int k = (xj * xs) & 127;
      ar += 2.f * (Sre[xj] * tc[k] - Sim[xj] * tsn[k]);
    }
  }
  ws[WS_T + idx] = ar; ws[WS_T + idx + 1] = ai;   // in-place per (b,y) slice
}

// ---------------- inverse stage 2 + epilogue ----------------
__global__ void fnde_final(const float* __restrict__ z, const float* __restrict__ ws,
                           float* __restrict__ out) {
  const int bid = blockIdx.x;             // b*128 + xs
  const int b = bid >> 7, xs = bid & 127;
  const int t = threadIdx.x;              // 128 (ys)
  __shared__ float Tre[16], Tim[16], tc[128], tsn[128];
  sincosf((float)t * kTheta, &tsn[t], &tc[t]);
  if (t < 16) {
    int idx = ((b * 128 + xs) * 16 + t) * 2;
    Tre[t] = ws[WS_T + idx]; Tim[t] = ws[WS_T + idx + 1];
  }
  __syncthreads();
  float acc = Tre[0];
  for (int y = 1; y < 16; ++y) {
    int k = (y * t) & 127;
    acc += 2.f * (Tre[y] * tc[k] - Tim[y] * tsn[k]);   // 2*Re(T * e^{+i})
  }
  float val = ws[WS_ALPHA] * z[b * 16384 + xs * 128 + t] + ws[WS_GAMMA]
            + acc * (1.f / 16384.f);
  out[b * 16384 + xs * 128 + t] = val;
}

}  // namespace

extern "C" void kernel_launch(void* const* d_in, const int* in_sizes, int n_in,
                              void* d_out, int out_size, void* d_ws, size_t ws_size,
                              hipStream_t stream) {
  (void)in_sizes; (void)n_in; (void)out_size; (void)ws_size;
  const float* z   = (const float*)d_in[0];
  const float* lw  = (const float*)d_in[1];
  const float* lb  = (const float*)d_in[2];
  const float* w1  = (const float*)d_in[3];
  const float* w2  = (const float*)d_in[4];
  const float* flb = (const float*)d_in[5];
  const float* p1w = (const float*)d_in[6];
  const float* p1b = (const float*)d_in[7];
  const float* p2w = (const float*)d_in[8];
  const float* p2b = (const float*)d_in[9];
  const float* ts  = (const float*)d_in[10];
  float* ws = (float*)d_ws;
  float* out = (float*)d_out;

  fnde_phase1<<<dim3(kChainBlk + kFwd1Blk), dim3(256), 0, stream>>>(
      w1, w2, flb, lw, lb, ts, p1w, p2w, z, ws);
  fnde_mid<<<dim3(256), dim3(128), 0, stream>>>(lw, p1b, p2w, p2b, ws);
  fnde_final<<<dim3(2048), dim3(128), 0, stream>>>(z, ws, out);
}